// Round 1
// baseline (271.156 us; speedup 1.0000x reference)
//
#include <hip/hip_runtime.h>

// SSIM over (32,3,512,512) fp32 pairs, 11x11 gaussian sigma=1.5, VALID conv,
// scalar mean output. Fused separable conv: vertical pass in registers
// (thread owns a column pair), 5-channel v-stats staged in LDS (XOR-swizzled
// to kill the 16-way bank conflict of stride-8 float4 reads), horizontal
// 11-tap conv register-blocked 8 cols/thread, SSIM + mean fused in epilogue.

namespace {
constexpr int IMG_H = 512;
constexpr int IMG_W = 512;
constexpr int NIMG  = 96;            // B*C = 32*3
constexpr int OUT_H = 502;
constexpr int OUT_W = 502;
constexpr int RPB   = 64;            // output rows per block
constexpr int QR    = 4;             // output rows per inner iteration
constexpr int BUFW  = 544;           // 136 col4 slots * 4 floats (512 data + halo/pad)
constexpr double TOTAL = 24192384.0; // 96*502*502

// exp(-k^2/4.5) for k=5..1, computed to ~1e-9 (double), normalized at compile time
constexpr double U0 = 0.0038659201;
constexpr double U1 = 0.0285655007;
constexpr double U2 = 0.1353352832366127;
constexpr double U3 = 0.4111122898;
constexpr double U4 = 0.8007374026;
constexpr double S  = 1.0 + 2.0 * (U0 + U1 + U2 + U3 + U4);
}

__device__ __forceinline__ float2 f2fma(float w, float2 a, float2 c) {
    return make_float2(fmaf(w, a.x, c.x), fmaf(w, a.y, c.y));
}

__global__ __launch_bounds__(256, 3) void ssim_main(const float* __restrict__ img1,
                                                    const float* __restrict__ img2,
                                                    double* __restrict__ acc)
{
    __shared__ __align__(16) float vrow[QR][5][BUFW];
    __shared__ float red[4];

    const float g[11] = {
        (float)(U0/S), (float)(U1/S), (float)(U2/S), (float)(U3/S), (float)(U4/S),
        (float)(1.0/S),
        (float)(U4/S), (float)(U3/S), (float)(U2/S), (float)(U1/S), (float)(U0/S)
    };
    constexpr float C1 = 1e-4f;   // 0.01^2
    constexpr float C2 = 9e-4f;   // 0.03^2

    const int t   = threadIdx.x;
    const int z   = blockIdx.y;
    const int oy0 = blockIdx.x * RPB;
    const int row_end = min(oy0 + RPB, OUT_H);

    const float* p1 = img1 + (size_t)z * (IMG_H * IMG_W);
    const float* p2 = img2 + (size_t)z * (IMG_H * IMG_W);

    // phase-V: thread owns input cols 2t, 2t+1. Swizzled write offset.
    const int c4w  = t >> 1;
    const int woff = ((c4w ^ ((c4w >> 3) & 7)) << 2) + ((t & 1) << 1);

    // phase-H: thread = (row-in-group hq, 8-col group at cb). Swizzled read offsets.
    const int hq = t >> 6;
    const int hl = t & 63;
    const int cb = hl << 3;
    int roff[5];
    #pragma unroll
    for (int k = 0; k < 5; ++k) {
        int c4 = (cb >> 2) + k;
        roff[k] = (c4 ^ ((c4 >> 3) & 7)) << 2;
    }

    float local = 0.f;

    for (int r0 = oy0; r0 < row_end; r0 += QR) {
        // ---------------- phase V: vertical 11-tap conv, registers ----------------
        float2 xr[QR + 10], yr[QR + 10];
        #pragma unroll
        for (int j = 0; j < QR + 10; ++j) {
            int row = r0 + j;
            row = row < IMG_H ? row : IMG_H - 1;   // tail clamp; clamped rows unused by valid outputs
            const float2* a = (const float2*)(p1 + (size_t)row * IMG_W);
            const float2* b = (const float2*)(p2 + (size_t)row * IMG_W);
            xr[j] = a[t];
            yr[j] = b[t];
        }
        float2 vm1[QR], vm2[QR], v11[QR], v22[QR], v12[QR];
        #pragma unroll
        for (int q = 0; q < QR; ++q) {
            vm1[q] = make_float2(0.f, 0.f);
            vm2[q] = make_float2(0.f, 0.f);
            v11[q] = make_float2(0.f, 0.f);
            v22[q] = make_float2(0.f, 0.f);
            v12[q] = make_float2(0.f, 0.f);
        }
        #pragma unroll
        for (int j = 0; j < QR + 10; ++j) {
            float2 x = xr[j], y = yr[j];
            float2 xx = make_float2(x.x * x.x, x.y * x.y);
            float2 yy = make_float2(y.x * y.x, y.y * y.y);
            float2 xy = make_float2(x.x * y.x, x.y * y.y);
            #pragma unroll
            for (int q = 0; q < QR; ++q) {
                int k = j - q;
                if (k >= 0 && k < 11) {
                    float w = g[k];
                    vm1[q] = f2fma(w, x,  vm1[q]);
                    vm2[q] = f2fma(w, y,  vm2[q]);
                    v11[q] = f2fma(w, xx, v11[q]);
                    v22[q] = f2fma(w, yy, v22[q]);
                    v12[q] = f2fma(w, xy, v12[q]);
                }
            }
        }
        __syncthreads();   // previous iteration's phase-H reads complete
        #pragma unroll
        for (int q = 0; q < QR; ++q) {
            *(float2*)&vrow[q][0][woff] = vm1[q];
            *(float2*)&vrow[q][1][woff] = vm2[q];
            *(float2*)&vrow[q][2][woff] = v11[q];
            *(float2*)&vrow[q][3][woff] = v22[q];
            *(float2*)&vrow[q][4][woff] = v12[q];
        }
        __syncthreads();

        // ---------------- phase H: horizontal 11-tap conv + SSIM ----------------
        const int rr = r0 + hq;
        if (rr < row_end && cb < OUT_W) {
            float aa[5][8];
            #pragma unroll
            for (int ch = 0; ch < 5; ++ch) {
                const float* bc = &vrow[hq][ch][0];
                float f[20];
                #pragma unroll
                for (int k = 0; k < 5; ++k) {
                    float4 v = *(const float4*)(bc + roff[k]);
                    f[4*k+0] = v.x; f[4*k+1] = v.y; f[4*k+2] = v.z; f[4*k+3] = v.w;
                }
                #pragma unroll
                for (int j = 0; j < 8; ++j) {
                    float s = 0.f;
                    #pragma unroll
                    for (int k = 0; k < 11; ++k) s = fmaf(g[k], f[j + k], s);
                    aa[ch][j] = s;
                }
            }
            #pragma unroll
            for (int j = 0; j < 8; ++j) {
                if (cb + j < OUT_W) {
                    float mu1 = aa[0][j], mu2 = aa[1][j];
                    float e11 = aa[2][j], e22 = aa[3][j], e12 = aa[4][j];
                    float mu11 = mu1 * mu1;
                    float mu22 = mu2 * mu2;
                    float mu12 = mu1 * mu2;
                    float s1  = e11 - mu11;
                    float s2  = e22 - mu22;
                    float s12 = e12 - mu12;
                    float num = fmaf(2.f, mu12, C1) * fmaf(2.f, s12, C2);
                    float den = (mu11 + mu22 + C1) * (s1 + s2 + C2);
                    local += num / den;
                }
            }
        }
    }

    // ---------------- reduction: wave shuffle -> LDS -> double atomic ----------------
    #pragma unroll
    for (int off = 32; off > 0; off >>= 1) local += __shfl_down(local, off, 64);
    if ((t & 63) == 0) red[t >> 6] = local;
    __syncthreads();
    if (t == 0) {
        double s = (double)red[0] + (double)red[1] + (double)red[2] + (double)red[3];
        atomicAdd(acc, s);
    }
}

__global__ void ssim_fin(const double* __restrict__ acc, float* __restrict__ out)
{
    out[0] = (float)(acc[0] / TOTAL);
}

extern "C" void kernel_launch(void* const* d_in, const int* in_sizes, int n_in,
                              void* d_out, int out_size, void* d_ws, size_t ws_size,
                              hipStream_t stream)
{
    (void)in_sizes; (void)n_in; (void)out_size; (void)ws_size;
    const float* img1 = (const float*)d_in[0];
    const float* img2 = (const float*)d_in[1];
    double* acc = (double*)d_ws;

    hipMemsetAsync(d_ws, 0, sizeof(double), stream);
    dim3 grid((OUT_H + RPB - 1) / RPB, NIMG);
    hipLaunchKernelGGL(ssim_main, grid, dim3(256), 0, stream, img1, img2, acc);
    hipLaunchKernelGGL(ssim_fin, dim3(1), dim3(1), 0, stream, acc, (float*)d_out);
}